// Round 1
// baseline (66.335 us; speedup 1.0000x reference)
//
#include <hip/hip_runtime.h>
#include <math.h>

constexpr int B_ = 8;
constexpr int N_ = 8192;
constexpr int K_ = 100;
constexpr int PER_BATCH = N_ * K_;          // 819200
constexpr int BLOCK = 256;
constexpr int ITER = 8;
constexpr int ELEMS_PER_BLOCK = BLOCK * ITER;   // 2048
constexpr int BLOCKS_PER_BATCH = PER_BATCH / ELEMS_PER_BLOCK; // 400 (exact)

constexpr float R_MIN = 0.1f;
constexpr float R_MAX = 2.0f;

__global__ __launch_bounds__(BLOCK)
void repulsive_prior_kernel(const float* __restrict__ positions,  // [B,N,3]
                            const float* __restrict__ cell,       // [B,3,3]
                            const float* __restrict__ offsets,    // [B,N,K,3]
                            const int*   __restrict__ neighbors,  // [B,N,K] (int32 on device)
                            const int*   __restrict__ mask,       // [B,N,K]
                            float* __restrict__ out)              // [B]
{
    const int b     = blockIdx.x / BLOCKS_PER_BATCH;
    const int chunk = blockIdx.x % BLOCKS_PER_BATCH;
    const int base  = chunk * ELEMS_PER_BLOCK;

    // block-uniform cell matrix -> registers (scalar loads)
    const float* cb = cell + b * 9;
    const float c00 = cb[0], c01 = cb[1], c02 = cb[2];
    const float c10 = cb[3], c11 = cb[4], c12 = cb[5];
    const float c20 = cb[6], c21 = cb[7], c22 = cb[8];

    const float* __restrict__ pos_b = positions + (size_t)b * N_ * 3;
    const float* __restrict__ off_b = offsets   + (size_t)b * PER_BATCH * 3;
    const int*   __restrict__ nb_b  = neighbors + (size_t)b * PER_BATCH;
    const int*   __restrict__ mk_b  = mask      + (size_t)b * PER_BATCH;

    float acc = 0.0f;
    #pragma unroll
    for (int s = 0; s < ITER; ++s) {
        const int i = base + s * BLOCK + (int)threadIdx.x;   // < PER_BATCH (exact tiling)
        const int m = mk_b[i];
        const int j = nb_b[i];
        const float o0 = off_b[3 * i + 0];
        const float o1 = off_b[3 * i + 1];
        const float o2 = off_b[3 * i + 2];
        const int n = i / K_;                                 // const-div -> mul_hi
        const float pix = pos_b[3 * n + 0];
        const float piy = pos_b[3 * n + 1];
        const float piz = pos_b[3 * n + 2];
        const float pjx = pos_b[3 * j + 0];
        const float pjy = pos_b[3 * j + 1];
        const float pjz = pos_b[3 * j + 2];
        // vec = pos_j + offsets @ cell - pos_i
        const float vx = pjx + o0 * c00 + o1 * c10 + o2 * c20 - pix;
        const float vy = pjy + o0 * c01 + o1 * c11 + o2 * c21 - piy;
        const float vz = pjz + o0 * c02 + o1 * c12 + o2 * c22 - piz;
        const float sq = vx * vx + vy * vy + vz * vz;
        const float d  = sqrtf(sq);
        const bool keep = (m > 0) && (d >= R_MIN) && (d <= R_MAX);
        if (keep) acc += 1.0f / sq;
    }

    // wave64 reduce
    #pragma unroll
    for (int off = 32; off > 0; off >>= 1)
        acc += __shfl_down(acc, off, 64);

    __shared__ float wsum[BLOCK / 64];
    const int wave = threadIdx.x >> 6;
    const int lane = threadIdx.x & 63;
    if (lane == 0) wsum[wave] = acc;
    __syncthreads();
    if (threadIdx.x == 0) {
        float s = 0.0f;
        #pragma unroll
        for (int w = 0; w < BLOCK / 64; ++w) s += wsum[w];
        atomicAdd(&out[b], 0.5f * s);
    }
}

extern "C" void kernel_launch(void* const* d_in, const int* in_sizes, int n_in,
                              void* d_out, int out_size, void* d_ws, size_t ws_size,
                              hipStream_t stream) {
    const float* positions = (const float*)d_in[0];
    const float* cell      = (const float*)d_in[1];
    const float* offsets   = (const float*)d_in[2];
    const int*   neighbors = (const int*)d_in[3];
    const int*   mask      = (const int*)d_in[4];
    float* out = (float*)d_out;

    hipMemsetAsync(out, 0, out_size * sizeof(float), stream);

    const int grid = B_ * BLOCKS_PER_BATCH;   // 3200
    repulsive_prior_kernel<<<grid, BLOCK, 0, stream>>>(
        positions, cell, offsets, neighbors, mask, out);
}

// Round 2
// 45.497 us; speedup vs baseline: 1.4580x; 1.4580x over previous
//
#include <hip/hip_runtime.h>

constexpr int B_ = 8;
constexpr int N_ = 8192;
constexpr int K_ = 100;
constexpr int PER_BATCH = N_ * K_;                      // 819200 elements
constexpr int QUADS_PER_BATCH = PER_BATCH / 4;          // 204800
constexpr int BLOCK = 256;
constexpr int QPT = 4;                                  // quads per thread
constexpr int QUADS_PER_BLOCK = BLOCK * QPT;            // 1024
constexpr int BLOCKS_PER_BATCH = QUADS_PER_BATCH / QUADS_PER_BLOCK; // 200 exact
constexpr int GRID = B_ * BLOCKS_PER_BATCH;             // 1600

constexpr float RMIN2 = 0.01f;   // 0.1^2
constexpr float RMAX2 = 4.0f;    // 2.0^2

__global__ __launch_bounds__(BLOCK)
void repulsive_prior_kernel(const float* __restrict__ positions,  // [B,N,3]
                            const float* __restrict__ cell,       // [B,3,3]
                            const float* __restrict__ offsets,    // [B,N,K,3]
                            const int*   __restrict__ neighbors,  // [B,N,K]
                            const int*   __restrict__ mask,       // [B,N,K]
                            float* __restrict__ out)              // [B]
{
    const int bid   = blockIdx.x;
    const int b     = bid & 7;          // 8 batches <-> 8 XCDs (L2 locality for gathers)
    const int chunk = bid >> 3;         // 0..199
    const int qbase = chunk * QUADS_PER_BLOCK;

    const float* cb = cell + b * 9;
    const float c00 = cb[0], c01 = cb[1], c02 = cb[2];
    const float c10 = cb[3], c11 = cb[4], c12 = cb[5];
    const float c20 = cb[6], c21 = cb[7], c22 = cb[8];

    const float* __restrict__ pos_b = positions + (size_t)b * N_ * 3;
    const float* __restrict__ off_b = offsets   + (size_t)b * PER_BATCH * 3;
    const int*   __restrict__ nb_b  = neighbors + (size_t)b * PER_BATCH;
    const int*   __restrict__ mk_b  = mask      + (size_t)b * PER_BATCH;

    float acc = 0.0f;

    // math for one element given its gathered/streamed operands
    auto elem = [&](int j, int m, float o0, float o1, float o2,
                    float pix, float piy, float piz,
                    float pjx, float pjy, float pjz) {
        const float vx = pjx + o0 * c00 + o1 * c10 + o2 * c20 - pix;
        const float vy = pjy + o0 * c01 + o1 * c11 + o2 * c21 - piy;
        const float vz = pjz + o0 * c02 + o1 * c12 + o2 * c22 - piz;
        const float sq = vx * vx + vy * vy + vz * vz;
        const bool keep = (m > 0) & (sq >= RMIN2) & (sq <= RMAX2);
        acc += keep ? (1.0f / sq) : 0.0f;
    };

    #pragma unroll
    for (int s = 0; s < QPT; s += 2) {
        const int qid0 = qbase + (s + 0) * BLOCK + (int)threadIdx.x;
        const int qid1 = qbase + (s + 1) * BLOCK + (int)threadIdx.x;

        // ---- phase 1: all streaming loads (10 wide loads in flight) ----
        const int4   nb0 = *(const int4*)  (nb_b  + 4 * (size_t)qid0);
        const int4   nb1 = *(const int4*)  (nb_b  + 4 * (size_t)qid1);
        const int4   mk0 = *(const int4*)  (mk_b  + 4 * (size_t)qid0);
        const int4   mk1 = *(const int4*)  (mk_b  + 4 * (size_t)qid1);
        const float4 oa0 = *(const float4*)(off_b + 12 * (size_t)qid0);
        const float4 ob0 = *(const float4*)(off_b + 12 * (size_t)qid0 + 4);
        const float4 oc0 = *(const float4*)(off_b + 12 * (size_t)qid0 + 8);
        const float4 oa1 = *(const float4*)(off_b + 12 * (size_t)qid1);
        const float4 ob1 = *(const float4*)(off_b + 12 * (size_t)qid1 + 4);
        const float4 oc1 = *(const float4*)(off_b + 12 * (size_t)qid1 + 8);

        // ---- phase 2: pos_i (row-uniform within quad) + 8 gathers ----
        const int n0 = qid0 / 25;   // row index (25 quads per row of K=100)
        const int n1 = qid1 / 25;
        const float pix0 = pos_b[3 * n0 + 0], piy0 = pos_b[3 * n0 + 1], piz0 = pos_b[3 * n0 + 2];
        const float pix1 = pos_b[3 * n1 + 0], piy1 = pos_b[3 * n1 + 1], piz1 = pos_b[3 * n1 + 2];

        const int j00 = nb0.x, j01 = nb0.y, j02 = nb0.z, j03 = nb0.w;
        const int j10 = nb1.x, j11 = nb1.y, j12 = nb1.z, j13 = nb1.w;

        const float ax0 = pos_b[3*j00+0], ay0 = pos_b[3*j00+1], az0 = pos_b[3*j00+2];
        const float ax1 = pos_b[3*j01+0], ay1 = pos_b[3*j01+1], az1 = pos_b[3*j01+2];
        const float ax2 = pos_b[3*j02+0], ay2 = pos_b[3*j02+1], az2 = pos_b[3*j02+2];
        const float ax3 = pos_b[3*j03+0], ay3 = pos_b[3*j03+1], az3 = pos_b[3*j03+2];
        const float bx0 = pos_b[3*j10+0], by0 = pos_b[3*j10+1], bz0 = pos_b[3*j10+2];
        const float bx1 = pos_b[3*j11+0], by1 = pos_b[3*j11+1], bz1 = pos_b[3*j11+2];
        const float bx2 = pos_b[3*j12+0], by2 = pos_b[3*j12+1], bz2 = pos_b[3*j12+2];
        const float bx3 = pos_b[3*j13+0], by3 = pos_b[3*j13+1], bz3 = pos_b[3*j13+2];

        // ---- phase 3: math ----
        elem(j00, mk0.x, oa0.x, oa0.y, oa0.z, pix0, piy0, piz0, ax0, ay0, az0);
        elem(j01, mk0.y, oa0.w, ob0.x, ob0.y, pix0, piy0, piz0, ax1, ay1, az1);
        elem(j02, mk0.z, ob0.z, ob0.w, oc0.x, pix0, piy0, piz0, ax2, ay2, az2);
        elem(j03, mk0.w, oc0.y, oc0.z, oc0.w, pix0, piy0, piz0, ax3, ay3, az3);
        elem(j10, mk1.x, oa1.x, oa1.y, oa1.z, pix1, piy1, piz1, bx0, by0, bz0);
        elem(j11, mk1.y, oa1.w, ob1.x, ob1.y, pix1, piy1, piz1, bx1, by1, bz1);
        elem(j12, mk1.z, ob1.z, ob1.w, oc1.x, pix1, piy1, piz1, bx2, by2, bz2);
        elem(j13, mk1.w, oc1.y, oc1.z, oc1.w, pix1, piy1, piz1, bx3, by3, bz3);
    }

    // wave64 reduce
    #pragma unroll
    for (int off = 32; off > 0; off >>= 1)
        acc += __shfl_down(acc, off, 64);

    __shared__ float wsum[BLOCK / 64];
    const int wave = threadIdx.x >> 6;
    const int lane = threadIdx.x & 63;
    if (lane == 0) wsum[wave] = acc;
    __syncthreads();
    if (threadIdx.x == 0) {
        float s = 0.0f;
        #pragma unroll
        for (int w = 0; w < BLOCK / 64; ++w) s += wsum[w];
        atomicAdd(&out[b], 0.5f * s);
    }
}

extern "C" void kernel_launch(void* const* d_in, const int* in_sizes, int n_in,
                              void* d_out, int out_size, void* d_ws, size_t ws_size,
                              hipStream_t stream) {
    const float* positions = (const float*)d_in[0];
    const float* cell      = (const float*)d_in[1];
    const float* offsets   = (const float*)d_in[2];
    const int*   neighbors = (const int*)d_in[3];
    const int*   mask      = (const int*)d_in[4];
    float* out = (float*)d_out;

    hipMemsetAsync(out, 0, out_size * sizeof(float), stream);

    repulsive_prior_kernel<<<GRID, BLOCK, 0, stream>>>(
        positions, cell, offsets, neighbors, mask, out);
}